// Round 4
// baseline (1293.192 us; speedup 1.0000x reference)
//
#include <hip/hip_runtime.h>

#define B 32
#define S 2048
#define I 256
#define H 256

typedef _Float16 h2 __attribute__((ext_vector_type(2)));

__device__ __forceinline__ float fdot2(h2 a, h2 b, float c) {
#if __has_builtin(__builtin_amdgcn_fdot2)
    return __builtin_amdgcn_fdot2(a, b, c, false);
#else
    return fmaf((float)a[1], (float)b[1], fmaf((float)a[0], (float)b[0], c));
#endif
}

__device__ __forceinline__ h2 pkfma(h2 a, h2 b, h2 c) {
#if __has_builtin(__builtin_elementwise_fma)
    return __builtin_elementwise_fma(a, b, c);
#else
    return a * b + c;   // -ffp-contract fuses to v_pk_fma_f16
#endif
}

// lgkm-only workgroup barrier: __syncthreads() drains vmcnt(0) before
// s_barrier; our per-step global ops are thread-private columns so only LDS
// needs cross-wave visibility. imm 0xC07F = vmcnt(63) expcnt(7) lgkmcnt(0).
__device__ __forceinline__ void lds_barrier() {
    __asm__ __volatile__("" ::: "memory");
    __builtin_amdgcn_s_waitcnt(0xC07F);
    __builtin_amdgcn_s_barrier();
    __asm__ __volatile__("" ::: "memory");
}

__device__ __forceinline__ float fast_tanh(float x) {
    float e = __expf(2.0f * x);
    return 1.0f - __fdividef(2.0f, e + 1.0f);
}

// quad_perm(1,0,3,2): exchange with lane^1 within each quad
__device__ __forceinline__ float dpp_xor1(float x) {
    return __builtin_bit_cast(float, __builtin_amdgcn_mov_dpp(
        __builtin_bit_cast(int, x), 0xB1, 0xF, 0xF, false));
}
// quad_perm(2,3,0,1): exchange with lane^2 within each quad
__device__ __forceinline__ float dpp_xor2(float x) {
    return __builtin_bit_cast(float, __builtin_amdgcn_mov_dpp(
        __builtin_bit_cast(int, x), 0x4E, 0xF, 0xF, false));
}

// ---------------------------------------------------------------------------
// Phase 1: xw[m][n] = sum_k x[m][k]*Wxw[n][k] + Wxb[n]   (unchanged)
// ---------------------------------------------------------------------------
#define TM 64
#define TN 64
#define TK 32

__global__ __launch_bounds__(256) void phase1_gemm(
    const float* __restrict__ x, const float* __restrict__ Wxw,
    const float* __restrict__ Wxb, float* __restrict__ out)
{
    __shared__ __align__(16) float As[TK][TM + 4];
    __shared__ __align__(16) float Bs[TK][TN + 4];

    const int t  = threadIdx.x;
    const int tn = t & 15, tm = t >> 4;
    const int m0 = blockIdx.x * TM;
    const int n0 = blockIdx.y * TN;

    float acc[4][4] = {};
    float bias[4];
#pragma unroll
    for (int j = 0; j < 4; ++j) bias[j] = Wxb[n0 + 4 * tn + j];

    const int lr = t >> 3;
    const int lc = t & 7;

    for (int kt = 0; kt < I; kt += TK) {
#pragma unroll
        for (int hh = 0; hh < 2; ++hh) {
            const int m = lr + 32 * hh;
            float4 v = *(const float4*)(x   + (size_t)(m0 + m) * I + kt + 4 * lc);
            As[4 * lc + 0][m] = v.x; As[4 * lc + 1][m] = v.y;
            As[4 * lc + 2][m] = v.z; As[4 * lc + 3][m] = v.w;
            float4 w = *(const float4*)(Wxw + (size_t)(n0 + m) * I + kt + 4 * lc);
            Bs[4 * lc + 0][m] = w.x; Bs[4 * lc + 1][m] = w.y;
            Bs[4 * lc + 2][m] = w.z; Bs[4 * lc + 3][m] = w.w;
        }
        __syncthreads();
#pragma unroll
        for (int k = 0; k < TK; ++k) {
            float4 a = *(const float4*)&As[k][4 * tm];
            float4 b = *(const float4*)&Bs[k][4 * tn];
            float av[4] = {a.x, a.y, a.z, a.w};
            float bv[4] = {b.x, b.y, b.z, b.w};
#pragma unroll
            for (int i2 = 0; i2 < 4; ++i2)
#pragma unroll
                for (int j = 0; j < 4; ++j)
                    acc[i2][j] = fmaf(av[i2], bv[j], acc[i2][j]);
        }
        __syncthreads();
    }
#pragma unroll
    for (int i2 = 0; i2 < 4; ++i2) {
        float4 v = { acc[i2][0] + bias[0], acc[i2][1] + bias[1],
                     acc[i2][2] + bias[2], acc[i2][3] + bias[3] };
        *(float4*)(out + (size_t)(m0 + 4 * tm + i2) * H + n0 + 4 * tn) = v;
    }
}

// ---------------------------------------------------------------------------
// Phase 2: h = tanh(xw_s + h @ Whw^T), 2048 steps. 32 blocks x 256 threads.
//
// Structure (R3, kept): K split WITHIN each quad of lanes.
//   wave w owns rows [64w, 64w+64). lane l = (j = l>>2, q = l&3) computes
//   rows 64w+4j..+3 over k in [64q, 64q+64): 8 b128 reads/thread (4 distinct
//   addrs/instr, conflict-free via 144B quarter stride).
//   Partial reduce: 2-stage DPP quad butterfly (pure VALU, no LDS).
//   hsh double-buffered; ONE lgkm-only barrier per step publishes h.
//
// R4 (this round): MAC via v_pk_fma_f16 instead of v_dot2_f32_f16.
//   dot2 measured ~4 cyc/instr (R1+R3 VALUBusy both fit); pk_fma is plain
//   VOP3P, expected full rate (2 cyc wave64) -> MAC issue 512 -> 256 cyc.
//   4 pk-accumulators per row: each f16 slot sums only 8 products
//   (rounding walk ~5e-4), combined exactly via fdot2(acc,(1,1),.) in f32.
//   Empty-asm pin on wreg after init: closes any remat/reload path (VGPR
//   count next round is the diagnostic; AGPR parking is equally fine).
// ---------------------------------------------------------------------------
__global__ __launch_bounds__(256, 1) void phase2_rnn(
    const float* __restrict__ Whw, float* __restrict__ out)
{
    // h as f16, 4 k-quarters at 72-element (144 B) stride so the quad's 4
    // concurrent b128 reads hit bank groups 0/4/8/12: conflict-free.
    // Quarter qq holds h[64qq .. 64qq+63] in [0..63]; [64..71] is pad.
    __shared__ __align__(16) _Float16 hsh[2][4][72];

    const int b = blockIdx.x;
    const int t = threadIdx.x;
    const int w = t >> 6;        // wave: rows [64w, 64w+64)
    const int l = t & 63;
    const int j = l >> 2;        // quad: rows 64w+4j .. 64w+4j+3
    const int q = l & 3;         // k-quarter: k in [64q, 64q+64)

    // wreg[i][m] = W[64w+4j+i][64q + 2m .. 2m+1] as h2. Constant indices.
    h2 wreg[4][32];
#pragma unroll
    for (int i = 0; i < 4; ++i) {
        const float4* wp =
            (const float4*)(Whw + (size_t)(64 * w + 4 * j + i) * H + 64 * q);
#pragma unroll
        for (int m = 0; m < 16; ++m) {
            float4 f = wp[m];
            wreg[i][2 * m]     = h2{(_Float16)f.x, (_Float16)f.y};
            wreg[i][2 * m + 1] = h2{(_Float16)f.z, (_Float16)f.w};
        }
    }
    // Pin wreg: forbid remat-from-memory; allocator must keep it resident
    // (VGPR or AGPR -- both fine, VALU reads AGPRs on gfx90a+).
#pragma unroll
    for (int i = 0; i < 4; ++i)
#pragma unroll
        for (int m = 0; m < 32; ++m) {
            unsigned tmp = __builtin_bit_cast(unsigned, wreg[i][m]);
            __asm__("" : "+v"(tmp));
            wreg[i][m] = __builtin_bit_cast(h2, tmp);
        }

    hsh[0][w][l] = (_Float16)0.0f;   // h[t] lives at quarter w, slot l
    __syncthreads();

    // xw column t of batch b, read/written in place in d_out. 2-deep prefetch;
    // reads up to 2 steps past the end land in the h_last region (in bounds,
    // values unused).
    float* outb = out + (size_t)b * S * H + t;
    float*       op = outb;
    const float* lp = outb + 2 * (size_t)H;
    float xw0 = outb[0], xw1 = outb[(size_t)H];

    const h2 one2 = h2{(_Float16)1.0f, (_Float16)1.0f};

    float hv = 0.f;
    int p = 0;
    for (int s = 0; s < S; ++s) {
        float xwn = lp[0]; lp += H;          // prefetch xw for step s+2

        // MAC: 4 rows x 64 k (own quarter). 8 b128 reads, 128 v_pk_fma_f16.
        // acc[i][c]: f16-pair accumulator c for row i; 8 pk_fma per chain.
        const uint4* hp = (const uint4*)&hsh[p][q][0];
        h2 acc[4][4];
#pragma unroll
        for (int i = 0; i < 4; ++i)
#pragma unroll
            for (int c = 0; c < 4; ++c)
                acc[i][c] = h2{(_Float16)0.0f, (_Float16)0.0f};
#pragma unroll
        for (int u = 0; u < 8; ++u) {        // uint4 u covers k = 64q+8u ..
            uint4 v = hp[u];
            h2 q0 = __builtin_bit_cast(h2, v.x);
            h2 q1 = __builtin_bit_cast(h2, v.y);
            h2 q2 = __builtin_bit_cast(h2, v.z);
            h2 q3 = __builtin_bit_cast(h2, v.w);
#pragma unroll
            for (int i = 0; i < 4; ++i) {
                acc[i][0] = pkfma(wreg[i][4 * u + 0], q0, acc[i][0]);
                acc[i][1] = pkfma(wreg[i][4 * u + 1], q1, acc[i][1]);
                acc[i][2] = pkfma(wreg[i][4 * u + 2], q2, acc[i][2]);
                acc[i][3] = pkfma(wreg[i][4 * u + 3], q3, acc[i][3]);
            }
        }
        // Exact f32 combine: fdot2(acc,(1,1),c) adds the two f16 slots in f32.
        float accf[4];
#pragma unroll
        for (int i = 0; i < 4; ++i)
            accf[i] = fdot2(acc[i][0], one2,
                      fdot2(acc[i][1], one2,
                      fdot2(acc[i][2], one2,
                      fdot2(acc[i][3], one2, 0.0f))));
        float acc0 = accf[0], acc1 = accf[1], acc2 = accf[2], acc3 = accf[3];

        // Quad butterfly reduce: acc_i = partial of row 4j+i over quarter q.
        // Stage 1 (lane^1): keep rows with i&1 == q&1.
        float X  = (q & 1) ? acc0 : acc1;    // sent
        float Y  = (q & 1) ? acc2 : acc3;
        float U  = (q & 1) ? acc1 : acc0;    // kept
        float V  = (q & 1) ? acc3 : acc2;
        float Sa = U + dpp_xor1(X);          // row (q&1),   k-half {q, q^1}
        float Sb = V + dpp_xor1(Y);          // row 2+(q&1), k-half {q, q^1}
        // Stage 2 (lane^2): keep row with i&2 == q&2 -> final row = q.
        float X2 = (q & 2) ? Sa : Sb;        // sent
        float U2 = (q & 2) ? Sb : Sa;        // kept
        float sum = U2 + dpp_xor2(X2);       // full sum for row 64w+l == t

        hv = fast_tanh(xw0 + sum);
        op[0] = hv; op += H;                  // outputs[b,s,t]
        hsh[p ^ 1][w][l] = (_Float16)hv;      // publish h[t] in back buffer

        lds_barrier();                        // the ONE barrier per step
        p ^= 1;

        xw0 = xw1; xw1 = xwn;
    }
    out[(size_t)B * S * H + (size_t)b * H + t] = hv;   // h_last
}

// ---------------------------------------------------------------------------
extern "C" void kernel_launch(void* const* d_in, const int* in_sizes, int n_in,
                              void* d_out, int out_size, void* d_ws, size_t ws_size,
                              hipStream_t stream) {
    const float* x   = (const float*)d_in[0];
    const float* Wxw = (const float*)d_in[1];
    const float* Wxb = (const float*)d_in[2];
    const float* Whw = (const float*)d_in[3];
    float* out = (float*)d_out;

    dim3 g1(B * S / TM, H / TN);   // 1024 x 4
    phase1_gemm<<<g1, 256, 0, stream>>>(x, Wxw, Wxb, out);
    phase2_rnn<<<B, 256, 0, stream>>>(Whw, out);
}

// Round 5
// 1034.604 us; speedup vs baseline: 1.2499x; 1.2499x over previous
//
#include <hip/hip_runtime.h>

#define B 32
#define S 2048
#define I 256
#define H 256

typedef _Float16 h2 __attribute__((ext_vector_type(2)));

__device__ __forceinline__ float fdot2(h2 a, h2 b, float c) {
#if __has_builtin(__builtin_amdgcn_fdot2)
    return __builtin_amdgcn_fdot2(a, b, c, false);
#else
    return fmaf((float)a[1], (float)b[1], fmaf((float)a[0], (float)b[0], c));
#endif
}

// lgkm-only workgroup barrier: __syncthreads() drains vmcnt(0) before
// s_barrier; our per-step global ops are thread-private columns so only LDS
// needs cross-wave visibility. imm 0xC07F = vmcnt(63) expcnt(7) lgkmcnt(0).
__device__ __forceinline__ void lds_barrier() {
    __asm__ __volatile__("" ::: "memory");
    __builtin_amdgcn_s_waitcnt(0xC07F);
    __builtin_amdgcn_s_barrier();
    __asm__ __volatile__("" ::: "memory");
}

__device__ __forceinline__ float fast_tanh(float x) {
    float e = __expf(2.0f * x);
    return 1.0f - __fdividef(2.0f, e + 1.0f);
}

// quad_perm(1,0,3,2): exchange with lane^1 within each quad
__device__ __forceinline__ float dpp_xor1(float x) {
    return __builtin_bit_cast(float, __builtin_amdgcn_mov_dpp(
        __builtin_bit_cast(int, x), 0xB1, 0xF, 0xF, false));
}
// quad_perm(2,3,0,1): exchange with lane^2 within each quad
__device__ __forceinline__ float dpp_xor2(float x) {
    return __builtin_bit_cast(float, __builtin_amdgcn_mov_dpp(
        __builtin_bit_cast(int, x), 0x4E, 0xF, 0xF, false));
}

// ---------------------------------------------------------------------------
// Phase 1: xw[m][n] = sum_k x[m][k]*Wxw[n][k] + Wxb[n]
// R5: software-pipelined global loads (issue kt+1's loads right after the
// first sync, before compute) -- hides ~200-500 cyc HBM/L2 latency per kt
// that the old load->store->sync->compute order exposed.
// ---------------------------------------------------------------------------
#define TM 64
#define TN 64
#define TK 32

__global__ __launch_bounds__(256) void phase1_gemm(
    const float* __restrict__ x, const float* __restrict__ Wxw,
    const float* __restrict__ Wxb, float* __restrict__ out)
{
    __shared__ __align__(16) float As[TK][TM + 4];
    __shared__ __align__(16) float Bs[TK][TN + 4];

    const int t  = threadIdx.x;
    const int tn = t & 15, tm = t >> 4;
    const int m0 = blockIdx.x * TM;
    const int n0 = blockIdx.y * TN;

    float acc[4][4] = {};
    float bias[4];
#pragma unroll
    for (int j = 0; j < 4; ++j) bias[j] = Wxb[n0 + 4 * tn + j];

    const int lr = t >> 3;
    const int lc = t & 7;

    float4 va[2], vb[2];
#pragma unroll
    for (int hh = 0; hh < 2; ++hh) {             // prologue: tile kt=0
        const int m = lr + 32 * hh;
        va[hh] = *(const float4*)(x   + (size_t)(m0 + m) * I + 4 * lc);
        vb[hh] = *(const float4*)(Wxw + (size_t)(n0 + m) * I + 4 * lc);
    }

    for (int kt = 0; kt < I; kt += TK) {
#pragma unroll
        for (int hh = 0; hh < 2; ++hh) {         // regs -> LDS (transpose)
            const int m = lr + 32 * hh;
            float4 v = va[hh];
            As[4 * lc + 0][m] = v.x; As[4 * lc + 1][m] = v.y;
            As[4 * lc + 2][m] = v.z; As[4 * lc + 3][m] = v.w;
            float4 wv = vb[hh];
            Bs[4 * lc + 0][m] = wv.x; Bs[4 * lc + 1][m] = wv.y;
            Bs[4 * lc + 2][m] = wv.z; Bs[4 * lc + 3][m] = wv.w;
        }
        __syncthreads();
        if (kt + TK < I) {                       // prefetch tile kt+1
#pragma unroll
            for (int hh = 0; hh < 2; ++hh) {
                const int m = lr + 32 * hh;
                va[hh] = *(const float4*)(x   + (size_t)(m0 + m) * I + kt + TK + 4 * lc);
                vb[hh] = *(const float4*)(Wxw + (size_t)(n0 + m) * I + kt + TK + 4 * lc);
            }
        }
#pragma unroll
        for (int k = 0; k < TK; ++k) {
            float4 a = *(const float4*)&As[k][4 * tm];
            float4 b = *(const float4*)&Bs[k][4 * tn];
            float av[4] = {a.x, a.y, a.z, a.w};
            float bv[4] = {b.x, b.y, b.z, b.w};
#pragma unroll
            for (int i2 = 0; i2 < 4; ++i2)
#pragma unroll
                for (int j = 0; j < 4; ++j)
                    acc[i2][j] = fmaf(av[i2], bv[j], acc[i2][j]);
        }
        __syncthreads();
    }
#pragma unroll
    for (int i2 = 0; i2 < 4; ++i2) {
        float4 v = { acc[i2][0] + bias[0], acc[i2][1] + bias[1],
                     acc[i2][2] + bias[2], acc[i2][3] + bias[3] };
        *(float4*)(out + (size_t)(m0 + 4 * tm + i2) * H + n0 + 4 * tn) = v;
    }
}

// ---------------------------------------------------------------------------
// Phase 2: h = tanh(xw_s + h @ Whw^T), 2048 steps. 32 blocks x 256 threads.
//
// Rate facts (R1/R3/R4 measured): fdot2 AND pk_fma_f16 both issue ~4 cyc
// => 128 MAC/cyc/CU = the f32 VALU peak. MAC issue floor = 512 cyc/step.
// Structure (R3): K split WITHIN each quad. wave w owns rows [64w,64w+64);
// lane l=(j=l>>2,q=l&3) MACs 4 rows over k in [64q,64q+64): 8 b128 reads
// (conflict-free, 144B quarter stride), 128 fdot2. DPP quad butterfly
// reduce; hsh double-buffered; ONE lgkm-only barrier per step.
//
// R5: cndmask-free butterfly via permuted row assignment. Lane (j,q)
// computes rows 4j+(q^i) in acc_i. Then:
//   Sa = acc0 + xor1(acc1); Sb = acc2 + xor1(acc3); sum = Sa + xor2(Sb)
// lands the FULL sum of row 64w+l in lane l with zero selects. Add order
// per lane: (own-quarter + partner) + (pair) -- bit-identical to R3.
// Plus: unroll-2 step loop (static p), publish-before-store ordering.
// ---------------------------------------------------------------------------
__global__ __launch_bounds__(256, 1) void phase2_rnn(
    const float* __restrict__ Whw, float* __restrict__ out)
{
    // h as f16, 4 k-quarters at 72-element (144 B) stride so the quad's 4
    // concurrent b128 reads hit bank groups 0/4/8/12: conflict-free.
    __shared__ __align__(16) _Float16 hsh[2][4][72];

    const int b = blockIdx.x;
    const int t = threadIdx.x;
    const int w = t >> 6;        // wave: rows [64w, 64w+64)
    const int l = t & 63;
    const int j = l >> 2;        // quad: rows 64w+4j .. 64w+4j+3
    const int q = l & 3;         // k-quarter: k in [64q, 64q+64)

    // wreg[i][m] = W[64w+4j+(q^i)][64q + 2m .. 2m+1] as h2 (permuted rows).
    h2 wreg[4][32];
#pragma unroll
    for (int i = 0; i < 4; ++i) {
        const float4* wp =
            (const float4*)(Whw + (size_t)(64 * w + 4 * j + (q ^ i)) * H + 64 * q);
#pragma unroll
        for (int m = 0; m < 16; ++m) {
            float4 f = wp[m];
            wreg[i][2 * m]     = h2{(_Float16)f.x, (_Float16)f.y};
            wreg[i][2 * m + 1] = h2{(_Float16)f.z, (_Float16)f.w};
        }
    }
    // Pin wreg: forbid remat-from-memory (VGPR or AGPR residency both fine).
#pragma unroll
    for (int i = 0; i < 4; ++i)
#pragma unroll
        for (int m = 0; m < 32; ++m) {
            unsigned tmp = __builtin_bit_cast(unsigned, wreg[i][m]);
            __asm__("" : "+v"(tmp));
            wreg[i][m] = __builtin_bit_cast(h2, tmp);
        }

    hsh[0][w][l] = (_Float16)0.0f;   // h[t] lives at quarter w, slot l
    __syncthreads();

    // xw column t of batch b, read/written in place in d_out. 2-deep prefetch;
    // reads up to 2 steps past the end land in the h_last region (in bounds,
    // values unused).
    float* outb = out + (size_t)b * S * H + t;
    float*       op = outb;
    const float* lp = outb + 2 * (size_t)H;
    float xw0 = outb[0], xw1 = outb[(size_t)H];

    float hv = 0.f;
#pragma unroll 2
    for (int s = 0; s < S; ++s) {
        const int p = s & 1;                 // static under unroll-2
        float xwn = lp[0]; lp += H;          // prefetch xw for step s+2

        // MAC: 4 (permuted) rows x 64 k (own quarter). 8 b128, 128 fdot2.
        const uint4* hp = (const uint4*)&hsh[p][q][0];
        float acc0 = 0.f, acc1 = 0.f, acc2 = 0.f, acc3 = 0.f;
#pragma unroll
        for (int u = 0; u < 8; ++u) {        // uint4 u covers k = 64q+8u ..
            uint4 v = hp[u];
            h2 q0 = __builtin_bit_cast(h2, v.x);
            h2 q1 = __builtin_bit_cast(h2, v.y);
            h2 q2 = __builtin_bit_cast(h2, v.z);
            h2 q3 = __builtin_bit_cast(h2, v.w);
            acc0 = fdot2(wreg[0][4 * u + 0], q0, acc0);
            acc0 = fdot2(wreg[0][4 * u + 1], q1, acc0);
            acc0 = fdot2(wreg[0][4 * u + 2], q2, acc0);
            acc0 = fdot2(wreg[0][4 * u + 3], q3, acc0);
            acc1 = fdot2(wreg[1][4 * u + 0], q0, acc1);
            acc1 = fdot2(wreg[1][4 * u + 1], q1, acc1);
            acc1 = fdot2(wreg[1][4 * u + 2], q2, acc1);
            acc1 = fdot2(wreg[1][4 * u + 3], q3, acc1);
            acc2 = fdot2(wreg[2][4 * u + 0], q0, acc2);
            acc2 = fdot2(wreg[2][4 * u + 1], q1, acc2);
            acc2 = fdot2(wreg[2][4 * u + 2], q2, acc2);
            acc2 = fdot2(wreg[2][4 * u + 3], q3, acc2);
            acc3 = fdot2(wreg[3][4 * u + 0], q0, acc3);
            acc3 = fdot2(wreg[3][4 * u + 1], q1, acc3);
            acc3 = fdot2(wreg[3][4 * u + 2], q2, acc3);
            acc3 = fdot2(wreg[3][4 * u + 3], q3, acc3);
        }

        // Select-free quad butterfly (rows pre-permuted by q^i):
        // stage 1 (lane^1): acc0/acc1 swap roles automatically.
        float Sa  = acc0 + dpp_xor1(acc1);   // row q, quarters {q, q^1}
        float Sb  = acc2 + dpp_xor1(acc3);   // row q^2, quarters {q, q^1}
        float sum = Sa + dpp_xor2(Sb);       // full sum for row 64w+l == t

        hv = fast_tanh(xw0 + sum);
        hsh[p ^ 1][w][l] = (_Float16)hv;      // publish first (lgkm path)
        op[0] = hv; op += H;                  // outputs[b,s,t] (vm path)

        lds_barrier();                        // the ONE barrier per step

        xw0 = xw1; xw1 = xwn;
    }
    out[(size_t)B * S * H + (size_t)b * H + t] = hv;   // h_last
}

// ---------------------------------------------------------------------------
extern "C" void kernel_launch(void* const* d_in, const int* in_sizes, int n_in,
                              void* d_out, int out_size, void* d_ws, size_t ws_size,
                              hipStream_t stream) {
    const float* x   = (const float*)d_in[0];
    const float* Wxw = (const float*)d_in[1];
    const float* Wxb = (const float*)d_in[2];
    const float* Whw = (const float*)d_in[3];
    float* out = (float*)d_out;

    dim3 g1(B * S / TM, H / TN);   // 1024 x 4
    phase1_gemm<<<g1, 256, 0, stream>>>(x, Wxw, Wxb, out);
    phase2_rnn<<<B, 256, 0, stream>>>(Whw, out);
}

// Round 6
// 1029.108 us; speedup vs baseline: 1.2566x; 1.0053x over previous
//
#include <hip/hip_runtime.h>

#define B 32
#define S 2048
#define I 256
#define H 256

typedef _Float16 h2 __attribute__((ext_vector_type(2)));

__device__ __forceinline__ float fdot2(h2 a, h2 b, float c) {
#if __has_builtin(__builtin_amdgcn_fdot2)
    return __builtin_amdgcn_fdot2(a, b, c, false);
#else
    return fmaf((float)a[1], (float)b[1], fmaf((float)a[0], (float)b[0], c));
#endif
}

// lgkm-only workgroup barrier: __syncthreads() drains vmcnt(0) before
// s_barrier; all cross-thread deps in both kernels are LDS-only, and
// in-flight global prefetches are ordered by the compiler's vmcnt waits on
// their destination registers. imm 0xC07F = vmcnt(63) expcnt(7) lgkmcnt(0).
__device__ __forceinline__ void lds_barrier() {
    __asm__ __volatile__("" ::: "memory");
    __builtin_amdgcn_s_waitcnt(0xC07F);
    __builtin_amdgcn_s_barrier();
    __asm__ __volatile__("" ::: "memory");
}

// tanh via exp2 with folded constant: tanh(x) = 1 - 2/(1 + 2^(x*2*log2 e)).
// 5-instr chain (mul, exp, add, rcp, fma) vs 7 for the __expf form.
__device__ __forceinline__ float fast_tanh(float x) {
#if __has_builtin(__builtin_amdgcn_exp2f) && __has_builtin(__builtin_amdgcn_rcpf)
    float e = __builtin_amdgcn_exp2f(x * 2.8853900818f);   // e^(2x)
    float r = __builtin_amdgcn_rcpf(e + 1.0f);
    return fmaf(-2.0f, r, 1.0f);
#else
    float e = __expf(2.0f * x);
    return 1.0f - __fdividef(2.0f, e + 1.0f);
#endif
}

// quad_perm(1,0,3,2): exchange with lane^1 within each quad
__device__ __forceinline__ float dpp_xor1(float x) {
    return __builtin_bit_cast(float, __builtin_amdgcn_mov_dpp(
        __builtin_bit_cast(int, x), 0xB1, 0xF, 0xF, false));
}
// quad_perm(2,3,0,1): exchange with lane^2 within each quad
__device__ __forceinline__ float dpp_xor2(float x) {
    return __builtin_bit_cast(float, __builtin_amdgcn_mov_dpp(
        __builtin_bit_cast(int, x), 0x4E, 0xF, 0xF, false));
}

// ---------------------------------------------------------------------------
// Phase 1: xw[m][n] = sum_k x[m][k]*Wxw[n][k] + Wxb[n]
//
// R6: phase1 was LDS-READ-PIPE-bound, not latency-bound: 4x4 thread tile =
// 2 b128 per 16 FMA -> ~150 us of LDS pipe vs 55 us of FMA issue. Fix:
// 128x128 block tile, 8x8 per thread -> 4 b128 per 64 FMA (2x less LDS per
// FMA, ~75 us), plus lgkm-only barriers (the old bottom __syncthreads
// drained vmcnt(0), serializing the prefetched loads).
// ---------------------------------------------------------------------------
#define TM 128
#define TN 128
#define TK 32
#define LDP (TM + 4)    // padded leading dim (16B-aligned rows)

__global__ __launch_bounds__(256) void phase1_gemm(
    const float* __restrict__ x, const float* __restrict__ Wxw,
    const float* __restrict__ Wxb, float* __restrict__ out)
{
    __shared__ __align__(16) float As[TK][LDP];   // 33.8 KB total
    __shared__ __align__(16) float Bs[TK][LDP];

    const int t  = threadIdx.x;
    const int tn = t & 15, tm = t >> 4;
    const int m0 = blockIdx.x * TM;
    const int n0 = blockIdx.y * TN;

    float acc[8][8] = {};
    float bias[8];
#pragma unroll
    for (int j = 0; j < 4; ++j) {
        bias[j]     = Wxb[n0 + 4 * tn + j];
        bias[4 + j] = Wxb[n0 + 64 + 4 * tn + j];
    }

    const int lr = t >> 3;   // 0..31
    const int lc = t & 7;    // 0..7

    float4 va[4], vb[4];
#pragma unroll
    for (int hh = 0; hh < 4; ++hh) {             // prologue: tile kt=0
        const int m = lr + 32 * hh;
        va[hh] = *(const float4*)(x   + (size_t)(m0 + m) * I + 4 * lc);
        vb[hh] = *(const float4*)(Wxw + (size_t)(n0 + m) * I + 4 * lc);
    }

    for (int kt = 0; kt < I; kt += TK) {
#pragma unroll
        for (int hh = 0; hh < 4; ++hh) {         // regs -> LDS (transpose)
            const int m = lr + 32 * hh;
            float4 v = va[hh];
            As[4 * lc + 0][m] = v.x; As[4 * lc + 1][m] = v.y;
            As[4 * lc + 2][m] = v.z; As[4 * lc + 3][m] = v.w;
            float4 wv = vb[hh];
            Bs[4 * lc + 0][m] = wv.x; Bs[4 * lc + 1][m] = wv.y;
            Bs[4 * lc + 2][m] = wv.z; Bs[4 * lc + 3][m] = wv.w;
        }
        lds_barrier();
        if (kt + TK < I) {                       // prefetch tile kt+1
#pragma unroll
            for (int hh = 0; hh < 4; ++hh) {
                const int m = lr + 32 * hh;
                va[hh] = *(const float4*)(x   + (size_t)(m0 + m) * I + kt + TK + 4 * lc);
                vb[hh] = *(const float4*)(Wxw + (size_t)(n0 + m) * I + kt + TK + 4 * lc);
            }
        }
#pragma unroll
        for (int k = 0; k < TK; ++k) {
            float4 a0 = *(const float4*)&As[k][4 * tm];
            float4 a1 = *(const float4*)&As[k][4 * tm + 64];
            float4 b0 = *(const float4*)&Bs[k][4 * tn];
            float4 b1 = *(const float4*)&Bs[k][4 * tn + 64];
            float av[8] = {a0.x, a0.y, a0.z, a0.w, a1.x, a1.y, a1.z, a1.w};
            float bv[8] = {b0.x, b0.y, b0.z, b0.w, b1.x, b1.y, b1.z, b1.w};
#pragma unroll
            for (int i2 = 0; i2 < 8; ++i2)
#pragma unroll
                for (int j = 0; j < 8; ++j)
                    acc[i2][j] = fmaf(av[i2], bv[j], acc[i2][j]);
        }
        lds_barrier();
    }
#pragma unroll
    for (int hi = 0; hi < 2; ++hi) {
#pragma unroll
        for (int i2 = 0; i2 < 4; ++i2) {
            const int r = m0 + 64 * hi + 4 * tm + i2;
            float4 v0 = { acc[4 * hi + i2][0] + bias[0], acc[4 * hi + i2][1] + bias[1],
                          acc[4 * hi + i2][2] + bias[2], acc[4 * hi + i2][3] + bias[3] };
            float4 v1 = { acc[4 * hi + i2][4] + bias[4], acc[4 * hi + i2][5] + bias[5],
                          acc[4 * hi + i2][6] + bias[6], acc[4 * hi + i2][7] + bias[7] };
            *(float4*)(out + (size_t)r * H + n0 + 4 * tn)      = v0;
            *(float4*)(out + (size_t)r * H + n0 + 64 + 4 * tn) = v1;
        }
    }
}

// ---------------------------------------------------------------------------
// Phase 2: h = tanh(xw_s + h @ Whw^T), 2048 steps. 32 blocks x 256 threads.
//
// Rate facts (R1/R3/R4 measured): fdot2 AND pk_fma_f16 both issue ~4 cyc
// => 128 MAC/cyc/CU = the f32 VALU peak. MAC issue floor = 512 cyc/step.
// Structure: K split WITHIN each quad. wave w owns rows [64w,64w+64);
// lane l=(j=l>>2,q=l&3) MACs 4 permuted rows 4j+(q^i) over k in
// [64q,64q+64): 8 b128 reads (conflict-free, 144B quarter stride),
// 128 fdot2. Select-free DPP quad butterfly lands row 64w+l's full sum in
// lane l. hsh double-buffered; ONE lgkm-only barrier per step.
// R5 measured: 988 cyc/step = 634 busy + 354 stall (barrier+LDS latency,
// lockstep-shared across waves -> wave-count games don't help).
// R6: tanh chain shortened (exp2+rcp+fma).
// ---------------------------------------------------------------------------
__global__ __launch_bounds__(256, 1) void phase2_rnn(
    const float* __restrict__ Whw, float* __restrict__ out)
{
    // h as f16, 4 k-quarters at 72-element (144 B) stride so the quad's 4
    // concurrent b128 reads hit bank groups 0/4/8/12: conflict-free.
    __shared__ __align__(16) _Float16 hsh[2][4][72];

    const int b = blockIdx.x;
    const int t = threadIdx.x;
    const int w = t >> 6;        // wave: rows [64w, 64w+64)
    const int l = t & 63;
    const int j = l >> 2;        // quad: rows 64w+4j .. 64w+4j+3
    const int q = l & 3;         // k-quarter: k in [64q, 64q+64)

    // wreg[i][m] = W[64w+4j+(q^i)][64q + 2m .. 2m+1] as h2 (permuted rows).
    h2 wreg[4][32];
#pragma unroll
    for (int i = 0; i < 4; ++i) {
        const float4* wp =
            (const float4*)(Whw + (size_t)(64 * w + 4 * j + (q ^ i)) * H + 64 * q);
#pragma unroll
        for (int m = 0; m < 16; ++m) {
            float4 f = wp[m];
            wreg[i][2 * m]     = h2{(_Float16)f.x, (_Float16)f.y};
            wreg[i][2 * m + 1] = h2{(_Float16)f.z, (_Float16)f.w};
        }
    }
    // Pin wreg: forbid remat-from-memory (VGPR or AGPR residency both fine).
#pragma unroll
    for (int i = 0; i < 4; ++i)
#pragma unroll
        for (int m = 0; m < 32; ++m) {
            unsigned tmp = __builtin_bit_cast(unsigned, wreg[i][m]);
            __asm__("" : "+v"(tmp));
            wreg[i][m] = __builtin_bit_cast(h2, tmp);
        }

    hsh[0][w][l] = (_Float16)0.0f;   // h[t] lives at quarter w, slot l
    __syncthreads();

    // xw column t of batch b, read/written in place in d_out. 2-deep prefetch;
    // reads up to 2 steps past the end land in the h_last region (in bounds,
    // values unused).
    float* outb = out + (size_t)b * S * H + t;
    float*       op = outb;
    const float* lp = outb + 2 * (size_t)H;
    float xw0 = outb[0], xw1 = outb[(size_t)H];

    float hv = 0.f;
#pragma unroll 2
    for (int s = 0; s < S; ++s) {
        const int p = s & 1;                 // static under unroll-2
        float xwn = lp[0]; lp += H;          // prefetch xw for step s+2

        // MAC: 4 (permuted) rows x 64 k (own quarter). 8 b128, 128 fdot2.
        const uint4* hp = (const uint4*)&hsh[p][q][0];
        float acc0 = 0.f, acc1 = 0.f, acc2 = 0.f, acc3 = 0.f;
#pragma unroll
        for (int u = 0; u < 8; ++u) {        // uint4 u covers k = 64q+8u ..
            uint4 v = hp[u];
            h2 q0 = __builtin_bit_cast(h2, v.x);
            h2 q1 = __builtin_bit_cast(h2, v.y);
            h2 q2 = __builtin_bit_cast(h2, v.z);
            h2 q3 = __builtin_bit_cast(h2, v.w);
            acc0 = fdot2(wreg[0][4 * u + 0], q0, acc0);
            acc0 = fdot2(wreg[0][4 * u + 1], q1, acc0);
            acc0 = fdot2(wreg[0][4 * u + 2], q2, acc0);
            acc0 = fdot2(wreg[0][4 * u + 3], q3, acc0);
            acc1 = fdot2(wreg[1][4 * u + 0], q0, acc1);
            acc1 = fdot2(wreg[1][4 * u + 1], q1, acc1);
            acc1 = fdot2(wreg[1][4 * u + 2], q2, acc1);
            acc1 = fdot2(wreg[1][4 * u + 3], q3, acc1);
            acc2 = fdot2(wreg[2][4 * u + 0], q0, acc2);
            acc2 = fdot2(wreg[2][4 * u + 1], q1, acc2);
            acc2 = fdot2(wreg[2][4 * u + 2], q2, acc2);
            acc2 = fdot2(wreg[2][4 * u + 3], q3, acc2);
            acc3 = fdot2(wreg[3][4 * u + 0], q0, acc3);
            acc3 = fdot2(wreg[3][4 * u + 1], q1, acc3);
            acc3 = fdot2(wreg[3][4 * u + 2], q2, acc3);
            acc3 = fdot2(wreg[3][4 * u + 3], q3, acc3);
        }

        // Select-free quad butterfly (rows pre-permuted by q^i):
        float Sa  = acc0 + dpp_xor1(acc1);   // row q, quarters {q, q^1}
        float Sb  = acc2 + dpp_xor1(acc3);   // row q^2, quarters {q, q^1}
        float sum = Sa + dpp_xor2(Sb);       // full sum for row 64w+l == t

        hv = fast_tanh(xw0 + sum);
        hsh[p ^ 1][w][l] = (_Float16)hv;      // publish first (lgkm path)
        op[0] = hv; op += H;                  // outputs[b,s,t] (vm path)

        lds_barrier();                        // the ONE barrier per step

        xw0 = xw1; xw1 = xwn;
    }
    out[(size_t)B * S * H + (size_t)b * H + t] = hv;   // h_last
}

// ---------------------------------------------------------------------------
extern "C" void kernel_launch(void* const* d_in, const int* in_sizes, int n_in,
                              void* d_out, int out_size, void* d_ws, size_t ws_size,
                              hipStream_t stream) {
    const float* x   = (const float*)d_in[0];
    const float* Wxw = (const float*)d_in[1];
    const float* Wxb = (const float*)d_in[2];
    const float* Whw = (const float*)d_in[3];
    float* out = (float*)d_out;

    dim3 g1(B * S / TM, H / TN);   // 512 x 2
    phase1_gemm<<<g1, 256, 0, stream>>>(x, Wxw, Wxb, out);
    phase2_rnn<<<B, 256, 0, stream>>>(Whw, out);
}